// Round 6
// baseline (2248.981 us; speedup 1.0000x reference)
//
#include <hip/hip_runtime.h>

// TreeLSTM (B=256, T=128, E=256, D=256) for MI355X / gfx950 — v4 (resubmit;
// prior rounds hit GPUAcquisitionTimeout, never executed).
//
// v4 = v3 with two fixes:
//  * pack_kernel Wp/Wg indexing: Wp,Wg are [256][256] (65536 elems each);
//    v3 indexed them as 131072-elem arrays -> OOB reads -> garbage front
//    weights -> absmax 0.79. Restored v2's correct transpose indexing.
//  * ppre_kernel: wave-uniform doT/doB ballots skip K=256 halves whose
//    operands are all value-slots (zeros) — halves ppre MFMA work for this
//    transition pattern (l is a stack value for 126/127 reduces).
//
// Structure (from v3):
//  plan_kernel  : register-packed symbolic stack (4xu32 tags + ver bitmask).
//  front_kernel : c_buf = x@Wp+bp ; h_buf = sigmoid(x@Wg+bg)*tanh(c_buf),
//                 M=16/wave, optional pre-packed x (xpk).
//  ppre_kernel  : bulk precompute of buffer-operand halves of reduce
//                 projections + br into Ppre[f][b][1280] (ring-buffered).
//  step_kernel  : serial; adds value-operand halves only (usually K=256).
//  out_kernel   : resolve final descriptor -> f32.
//
// Workspace layout (fixed part = 87,426,048 B):
//   Wr_t  u32 [1280][512]        2,621,440 @ 0
//   Wpg   u32 [512][256]           524,288 @ 2,621,440
//   h_buf u32 [32768][256]      33,554,432 @ 3,145,728
//   c_buf f32 [32768][256]      33,554,432 @ 36,700,160
//   vstkH u32 [32][256][256]     8,388,608 @ 70,254,592   (slot 31 = zeros)
//   vstkC f32 [32][256][256]     8,388,608 @ 78,643,200
//   planL/R/W i32 [128][256]   3 x 131,072 @ 87,031,808
//   fdesc i32 [256]                  1,024 @ 87,425,024
//   [optional] xpk u32 [32768][256]  33,554,432
//   [optional] Ppre f32 ring [R][256][1280]  R x 1,310,720

typedef unsigned int u32;
typedef short s16x8 __attribute__((ext_vector_type(8)));
typedef float f32x4 __attribute__((ext_vector_type(4)));

#define MFMA16(a, b, c) __builtin_amdgcn_mfma_f32_16x16x32_bf16((a), (b), (c), 0, 0, 0)

static __device__ __forceinline__ unsigned short f2bf(float x) {
  u32 u = __builtin_bit_cast(u32, x);
  u += 0x7fffu + ((u >> 16) & 1u);  // round-to-nearest-even
  return (unsigned short)(u >> 16);
}
static __device__ __forceinline__ float bf2f(unsigned short s) {
  u32 u = ((u32)s) << 16;
  return __builtin_bit_cast(float, u);
}
static __device__ __forceinline__ u32 packhl(float x) {
  unsigned short hi = f2bf(x);
  unsigned short lo = f2bf(x - bf2f(hi));
  return ((u32)hi << 16) | (u32)lo;
}
static __device__ __forceinline__ float unpackhl(u32 p) {
  return bf2f((unsigned short)(p >> 16)) + bf2f((unsigned short)(p & 0xffffu));
}
static __device__ __forceinline__ void unpack8(uint4 a, uint4 b, s16x8 &hi, s16x8 &lo) {
  hi[0] = (short)(a.x >> 16); lo[0] = (short)a.x;
  hi[1] = (short)(a.y >> 16); lo[1] = (short)a.y;
  hi[2] = (short)(a.z >> 16); lo[2] = (short)a.z;
  hi[3] = (short)(a.w >> 16); lo[3] = (short)a.w;
  hi[4] = (short)(b.x >> 16); lo[4] = (short)b.x;
  hi[5] = (short)(b.y >> 16); lo[5] = (short)b.y;
  hi[6] = (short)(b.z >> 16); lo[6] = (short)b.z;
  hi[7] = (short)(b.w >> 16); lo[7] = (short)b.w;
}
static __device__ __forceinline__ void split8(const float *w, s16x8 &hi, s16x8 &lo) {
#pragma unroll
  for (int i = 0; i < 8; i++) {
    unsigned short h = f2bf(w[i]);
    hi[i] = (short)h;
    lo[i] = (short)f2bf(w[i] - bf2f(h));
  }
}
static __device__ __forceinline__ float sigm(float x) { return 1.0f / (1.0f + expf(-x)); }
// value-slot index from 16-bit code: pos=code&15, ver=(code>>4)&1 -> slot=pos*2+ver
static __device__ __forceinline__ int vslot(int code) {
  return (code & 15) * 2 + ((code >> 4) & 1);
}

// ---------------------------------------------------------------- pack
__global__ __launch_bounds__(256) void pack_kernel(
    const float *__restrict__ Wp, const float *__restrict__ Wg,
    const float *__restrict__ Wr, const float *__restrict__ x,
    u32 *__restrict__ Wpg_t, u32 *__restrict__ Wr_t, u32 *__restrict__ xpk,
    u32 *__restrict__ vstkH, float *__restrict__ vstkC, int do_x) {
  int tid = blockIdx.x * 256 + threadIdx.x;
  if (tid < 131072) {  // Wp|Wg: each [256 E][256 D]; write Wpg_t[col][k]
    int isg = tid >= 65536;
    int s = tid & 65535;
    int k = s >> 8, col = s & 255;
    float v = isg ? Wg[s] : Wp[s];
    Wpg_t[(isg ? 256 + col : col) * 256 + k] = packhl(v);
  }
  if (tid < 655360) {  // Wr [512][1280] read-linear, write Wr_t[col][k]
    int k = tid / 1280;
    int col = tid - k * 1280;
    Wr_t[col * 512 + k] = packhl(Wr[tid]);
  }
  if (tid < 65536) {  // zero value-slot 31 (ZCODE target / dummy-A zeros)
    vstkH[31 * 65536 + tid] = 0u;
    vstkC[31 * 65536 + tid] = 0.0f;
  }
  if (do_x && tid < 8388608) xpk[tid] = packhl(x[tid]);
}

// ---------------------------------------------------------------- plan
// Register-packed symbolic stack: 16 entries x 8 bits in t0..t3; ver bitmask.
// entry: bit7=1 -> value slot (bits0-3 pos, bit4 ver); bit7=0 -> buffer row.
__global__ __launch_bounds__(256) void plan_kernel(
    const int *__restrict__ trans, int *__restrict__ pL, int *__restrict__ pR,
    int *__restrict__ pW, int *__restrict__ fdesc) {
  int b = threadIdx.x;
  u32 t0 = 0x9F9F9F9Fu, t1 = t0, t2 = t0, t3 = t0;  // all ZCODE8 (pos15,ver1)
  u32 verb = 0;
  int ptr = 0, bptr = 127;

  auto get = [&](int p) -> u32 {
    u32 w = p < 8 ? (p < 4 ? t0 : t1) : (p < 12 ? t2 : t3);
    return (w >> ((p & 3) * 8)) & 0xffu;
  };
  auto set = [&](int p, u32 e) {
    u32 sh = (u32)(p & 3) * 8u;
    u32 m = ~(0xffu << sh);
    u32 nv = e << sh;
    int ws = p >> 2;
    t0 = ws == 0 ? (t0 & m) | nv : t0;
    t1 = ws == 1 ? (t1 & m) | nv : t1;
    t2 = ws == 2 ? (t2 & m) | nv : t2;
    t3 = ws == 3 ? (t3 & m) | nv : t3;
  };
  auto dostep = [&](int tr, int &l, int &r, int &w) {
    if (tr == 0) {
      int pos = min(ptr, 15);
      set(pos, (u32)(bptr & 127));
      ptr++; bptr--;
    } else {
      int pl = min(max(ptr - 2, 0), 15);
      int pr = min(max(ptr - 1, 0), 15);
      l = (int)get(pl);
      r = (int)get(pr);
      u32 v = ((verb >> pl) & 1u) ^ 1u;
      verb = (verb & ~(1u << pl)) | (v << pl);
      set(pl, 0x80u | (v << 4) | (u32)pl);
      w = pl * 2 + (int)v;
      ptr--;
    }
  };
  auto ext = [&](int e) -> int { return (e & 0x80) ? (0x8000 | (e & 0x1f)) : e; };

  for (int f = 0; f < 128; ++f) {
    int l = 0x9F, r = 0x9F, w = -1;
    dostep(trans[(2 * f) * 256 + b], l, r, w);
    if (2 * f + 1 < 255) dostep(trans[(2 * f + 1) * 256 + b], l, r, w);
    pL[f * 256 + b] = ext(l);
    pR[f * 256 + b] = ext(r);
    pW[f * 256 + b] = w;
  }
  fdesc[b] = ext((int)get(min(max(ptr - 1, 0), 15)));
}

// ---------------------------------------------------------------- front GEMM
// 1 wave per wg; tile M=16 x 128 d-cols of BOTH Wp and Wg panels.
template <int UX>
__global__ __launch_bounds__(64) void front_kernel(
    const float *__restrict__ x, const u32 *__restrict__ xpk,
    const u32 *__restrict__ Wpg, const float *__restrict__ bp,
    const float *__restrict__ bg, u32 *__restrict__ h_buf,
    float *__restrict__ c_buf) {
  const int lane = threadIdx.x;
  const int rbase = blockIdx.x * 16;
  const int y = blockIdx.y;  // 0/1 -> d cols [y*128, y*128+128)
  const int rlo = lane & 15;
  const int khi = (lane >> 4) * 8;

  f32x4 z = {0.f, 0.f, 0.f, 0.f};
  f32x4 aP[8], aG[8];
#pragma unroll
  for (int i = 0; i < 8; i++) { aP[i] = z; aG[i] = z; }

#pragma unroll 2
  for (int kt = 0; kt < 8; ++kt) {
    int k = kt * 32 + khi;
    s16x8 Ah, Al;
    if (UX) {
      const u32 *ap = xpk + (rbase + rlo) * 256 + k;
      uint4 a0 = *(const uint4 *)ap, a1 = *(const uint4 *)(ap + 4);
      unpack8(a0, a1, Ah, Al);
    } else {
      const float *ap = x + (rbase + rlo) * 256 + k;
      float4 v0 = *(const float4 *)ap;
      float4 v1 = *(const float4 *)(ap + 4);
      float w[8] = {v0.x, v0.y, v0.z, v0.w, v1.x, v1.y, v1.z, v1.w};
      split8(w, Ah, Al);
    }
#pragma unroll
    for (int nt = 0; nt < 8; ++nt) {
      int colP = y * 128 + nt * 16 + rlo;
      {
        const u32 *wp = Wpg + colP * 256 + k;
        uint4 q0 = *(const uint4 *)wp, q1 = *(const uint4 *)(wp + 4);
        s16x8 Bh, Bl;
        unpack8(q0, q1, Bh, Bl);
        aP[nt] = MFMA16(Ah, Bh, aP[nt]);
        aP[nt] = MFMA16(Ah, Bl, aP[nt]);
        aP[nt] = MFMA16(Al, Bh, aP[nt]);
      }
      {
        const u32 *wg = Wpg + (256 + colP) * 256 + k;
        uint4 q0 = *(const uint4 *)wg, q1 = *(const uint4 *)(wg + 4);
        s16x8 Bh, Bl;
        unpack8(q0, q1, Bh, Bl);
        aG[nt] = MFMA16(Ah, Bh, aG[nt]);
        aG[nt] = MFMA16(Ah, Bl, aG[nt]);
        aG[nt] = MFMA16(Al, Bh, aG[nt]);
      }
    }
  }
  // epilogue: C/D col=lane&15, row=(lane>>4)*4+reg
#pragma unroll
  for (int nt = 0; nt < 8; ++nt) {
    int d = y * 128 + nt * 16 + rlo;
    float bpd = bp[d], bgd = bg[d];
#pragma unroll
    for (int ri = 0; ri < 4; ++ri) {
      int r = rbase + (lane >> 4) * 4 + ri;
      float cv = aP[nt][ri] + bpd;
      float gv = aG[nt][ri] + bgd;
      c_buf[r * 256 + d] = cv;
      h_buf[r * 256 + d] = packhl(sigm(gv) * tanhf(cv));
    }
  }
}

#define KSTEP_BODY(SRC, KOFF)                                                \
  {                                                                          \
    const u32 *s = (SRC) + kt * 32 + khi;                                    \
    uint4 a0 = *(const uint4 *)s, a1 = *(const uint4 *)(s + 4);              \
    s16x8 Ah, Al;                                                            \
    unpack8(a0, a1, Ah, Al);                                                 \
    int kk = (KOFF) + kt * 32 + khi;                                         \
    {                                                                        \
      const u32 *wp = Wr_t + gcol0 * 512 + kk;                               \
      uint4 q0 = *(const uint4 *)wp, q1 = *(const uint4 *)(wp + 4);          \
      s16x8 Bh, Bl;                                                          \
      unpack8(q0, q1, Bh, Bl);                                               \
      acc0 = MFMA16(Ah, Bh, acc0);                                           \
      acc0 = MFMA16(Ah, Bl, acc0);                                           \
      acc0 = MFMA16(Al, Bh, acc0);                                           \
    }                                                                        \
    {                                                                        \
      const u32 *wp = Wr_t + gcol1 * 512 + kk;                               \
      uint4 q0 = *(const uint4 *)wp, q1 = *(const uint4 *)(wp + 4);          \
      s16x8 Bh, Bl;                                                          \
      unpack8(q0, q1, Bh, Bl);                                               \
      acc1 = MFMA16(Ah, Bh, acc1);                                           \
      acc1 = MFMA16(Ah, Bl, acc1);                                           \
      acc1 = MFMA16(Al, Bh, acc1);                                           \
    }                                                                        \
    {                                                                        \
      const u32 *wp = Wr_t + gcol2 * 512 + kk;                               \
      uint4 q0 = *(const uint4 *)wp, q1 = *(const uint4 *)(wp + 4);          \
      s16x8 Bh, Bl;                                                          \
      unpack8(q0, q1, Bh, Bl);                                               \
      acc2 = MFMA16(Ah, Bh, acc2);                                           \
      acc2 = MFMA16(Ah, Bl, acc2);                                           \
      acc2 = MFMA16(Al, Bh, acc2);                                           \
    }                                                                        \
  }

// ---------------------------------------------------------------- ppre (bulk)
// Fold BUFFER-operand halves + br into Ppre[f][b][1280]; value-operand halves
// contribute zeros (added by the serial step). Ballots skip dead halves.
__global__ __launch_bounds__(64) void ppre_kernel(
    const float *__restrict__ br, const u32 *__restrict__ Wr_t,
    const u32 *__restrict__ h_buf, const u32 *__restrict__ vzero,
    const int *__restrict__ pL, const int *__restrict__ pR,
    const int *__restrict__ pW, float *__restrict__ ppre) {
  const int c = blockIdx.x;
  const int fl = blockIdx.y >> 4;
  const int g = blockIdx.y & 15;
  const int lane = threadIdx.x;
  const int b0 = g * 16;
  const int b = b0 + (lane & 15);

  const int lc = pL[fl * 256 + b];
  const int rc = pR[fl * 256 + b];
  const int w = pW[fl * 256 + b];
  if (__ballot(w >= 0) == 0ull) return;

  const bool lbuf = (lc & 0x8000) == 0;
  const bool rbuf = (rc & 0x8000) == 0;
  const u32 *srcT = lbuf ? h_buf + (((b << 7) + (lc & 127)) << 8) : vzero + (b << 8);
  const u32 *srcB = rbuf ? h_buf + (((b << 7) + (rc & 127)) << 8) : vzero + (b << 8);
  const bool doT = __ballot(w >= 0 && lbuf) != 0ull;
  const bool doB = __ballot(w >= 0 && rbuf) != 0ull;

  const int khi = (lane >> 4) * 8;
  const int cl = lane & 15;
  const int v2c = 32 + cl;
  const int gcol0 = (cl >> 3) * 256 + c * 8 + (cl & 7);
  const int gcol1 = ((16 + cl) >> 3) * 256 + c * 8 + (cl & 7);
  const int gcol2 = (v2c < 40) ? (v2c >> 3) * 256 + c * 8 + (v2c & 7) : 0;

  f32x4 acc0 = {0.f, 0.f, 0.f, 0.f}, acc1 = acc0, acc2 = acc0;
  if (doT) {
#pragma unroll 4
    for (int kt = 0; kt < 8; ++kt) KSTEP_BODY(srcT, 0)
  }
  if (doB) {
#pragma unroll 4
    for (int kt = 0; kt < 8; ++kt) KSTEP_BODY(srcB, 256)
  }

  int wcs[4];
#pragma unroll
  for (int ri = 0; ri < 4; ++ri) wcs[ri] = __shfl(w, (lane >> 4) * 4 + ri);
  float br0 = br[gcol0], br1 = br[gcol1], br2 = br[gcol2];
  float *pr = ppre + (size_t)fl * 327680;
#pragma unroll
  for (int ri = 0; ri < 4; ++ri) {
    if (wcs[ri] >= 0) {
      int b2 = b0 + (lane >> 4) * 4 + ri;
      float *row = pr + b2 * 1280;
      row[gcol0] = acc0[ri] + br0;
      row[gcol1] = acc1[ri] + br1;
      if (v2c < 40) row[gcol2] = acc2[ri] + br2;
    }
  }
}

// ---------------------------------------------------------------- serial step
// PPRE=1: value-operand halves only (buffer halves + br live in Ppre).
// PPRE=0: full-K=512 fallback.
template <int PPRE>
__global__ __launch_bounds__(64) void step_kernel(
    const float *__restrict__ br, const u32 *__restrict__ Wr_t,
    const u32 *__restrict__ h_buf, const float *__restrict__ c_buf,
    u32 *__restrict__ vstkH, float *__restrict__ vstkC,
    const u32 *__restrict__ vzero, const int *__restrict__ pL,
    const int *__restrict__ pR, const int *__restrict__ pW,
    const float *__restrict__ ppre) {
  const int c = blockIdx.x;
  const int g = blockIdx.y;
  const int lane = threadIdx.x;
  const int b0 = g * 16;
  const int b = b0 + (lane & 15);

  const int lc = pL[b];
  const int rc = pR[b];
  const int w = pW[b];
  if (__ballot(w >= 0) == 0ull) return;

  const bool lval = (lc & 0x8000) != 0;
  const bool rval = (rc & 0x8000) != 0;
  const u32 *srcT, *srcB;
  if (PPRE) {
    srcT = lval ? vstkH + ((vslot(lc) * 256 + b) << 8) : vzero + (b << 8);
    srcB = rval ? vstkH + ((vslot(rc) * 256 + b) << 8) : vzero + (b << 8);
  } else {
    srcT = lval ? vstkH + ((vslot(lc) * 256 + b) << 8)
                : h_buf + (((b << 7) + (lc & 127)) << 8);
    srcB = rval ? vstkH + ((vslot(rc) * 256 + b) << 8)
                : h_buf + (((b << 7) + (rc & 127)) << 8);
  }
  const bool doT = PPRE ? (__ballot(w >= 0 && lval) != 0ull) : true;
  const bool doB = PPRE ? (__ballot(w >= 0 && rval) != 0ull) : true;

  const int khi = (lane >> 4) * 8;
  const int cl = lane & 15;
  const int v2c = 32 + cl;
  const int gcol0 = (cl >> 3) * 256 + c * 8 + (cl & 7);
  const int gcol1 = ((16 + cl) >> 3) * 256 + c * 8 + (cl & 7);
  const int gcol2 = (v2c < 40) ? (v2c >> 3) * 256 + c * 8 + (v2c & 7) : 0;

  f32x4 acc0 = {0.f, 0.f, 0.f, 0.f}, acc1 = acc0, acc2 = acc0;
  if (doT) {
#pragma unroll 4
    for (int kt = 0; kt < 8; ++kt) KSTEP_BODY(srcT, 0)
  }
  if (doB) {
#pragma unroll 4
    for (int kt = 0; kt < 8; ++kt) KSTEP_BODY(srcB, 256)
  }

  // cell: out-dim j: i=acc0[col j], f_l=acc0[col 8+j], f_r=acc1[col j],
  //       g=acc1[col 8+j], o=acc2[col j]; C/D row=(lane>>4)*4+reg
  f32x4 flv, gv;
#pragma unroll
  for (int ri = 0; ri < 4; ++ri) {
    flv[ri] = __shfl_xor(acc0[ri], 8);
    gv[ri] = __shfl_xor(acc1[ri], 8);
  }
  int lcs[4], rcs[4], wcs[4];
#pragma unroll
  for (int ri = 0; ri < 4; ++ri) {
    int rr = (lane >> 4) * 4 + ri;
    lcs[ri] = __shfl(lc, rr);
    rcs[ri] = __shfl(rc, rr);
    wcs[ri] = __shfl(w, rr);
  }
  int colj = lane & 15;
  if (colj < 8) {
    int d = c * 8 + colj;
    float brI = 0, brFl = 0, brFr = 0, brG = 0, brO = 0;
    if (!PPRE) {
      brI = br[d]; brFl = br[256 + d]; brFr = br[512 + d];
      brG = br[768 + d]; brO = br[1024 + d];
    }
#pragma unroll
    for (int ri = 0; ri < 4; ++ri) {
      if (wcs[ri] >= 0) {
        int b2 = b0 + (lane >> 4) * 4 + ri;
        int lc2 = lcs[ri], rc2 = rcs[ri];
        float c_l = (lc2 & 0x8000)
                        ? vstkC[(vslot(lc2) * 256 + b2) * 256 + d]
                        : c_buf[(b2 * 128 + (lc2 & 127)) * 256 + d];
        float c_r = (rc2 & 0x8000)
                        ? vstkC[(vslot(rc2) * 256 + b2) * 256 + d]
                        : c_buf[(b2 * 128 + (rc2 & 127)) * 256 + d];
        float pI, pFl, pFr, pG, pO;
        if (PPRE) {
          const float *row = ppre + (size_t)b2 * 1280;
          pI = row[d]; pFl = row[256 + d]; pFr = row[512 + d];
          pG = row[768 + d]; pO = row[1024 + d];
        } else {
          pI = brI; pFl = brFl; pFr = brFr; pG = brG; pO = brO;
        }
        float ii = acc0[ri] + pI;
        float fl = flv[ri] + pFl;
        float fr = acc1[ri] + pFr;
        float gg = gv[ri] + pG;
        float oo = acc2[ri] + pO;
        float cv = sigm(ii) * tanhf(gg) + sigm(fl) * c_l + sigm(fr) * c_r;
        float hv = sigm(oo) * tanhf(cv);
        int sidx = wcs[ri];
        vstkH[(sidx * 256 + b2) * 256 + d] = packhl(hv);
        vstkC[(sidx * 256 + b2) * 256 + d] = cv;
      }
    }
  }
}

// ---------------------------------------------------------------- output
__global__ __launch_bounds__(256) void out_kernel(
    const int *__restrict__ fdesc, const u32 *__restrict__ h_buf,
    const u32 *__restrict__ vstkH, float *__restrict__ out) {
  int tid = blockIdx.x * 256 + threadIdx.x;  // 65536
  int b = tid >> 8, d = tid & 255;
  int code = fdesc[b];
  u32 hv = (code & 0x8000)
               ? vstkH[(vslot(code) * 256 + b) * 256 + d]
               : h_buf[(b * 128 + (code & 127)) * 256 + d];
  out[tid] = unpackhl(hv);
}

// ---------------------------------------------------------------- launch
extern "C" void kernel_launch(void *const *d_in, const int *in_sizes, int n_in,
                              void *d_out, int out_size, void *d_ws, size_t ws_size,
                              hipStream_t stream) {
  const float *x = (const float *)d_in[0];
  const float *Wp = (const float *)d_in[1];
  const float *bp = (const float *)d_in[2];
  const float *Wg = (const float *)d_in[3];
  const float *bg = (const float *)d_in[4];
  const float *Wr = (const float *)d_in[5];
  const float *br = (const float *)d_in[6];
  const int *trans = (const int *)d_in[7];
  float *out = (float *)d_out;

  char *ws = (char *)d_ws;
  u32 *Wr_t = (u32 *)(ws);
  u32 *Wpg = (u32 *)(ws + 2621440);
  u32 *h_buf = (u32 *)(ws + 3145728);
  float *c_buf = (float *)(ws + 36700160);
  u32 *vstkH = (u32 *)(ws + 70254592);
  float *vstkC = (float *)(ws + 78643200);
  int *planL = (int *)(ws + 87031808);
  int *planR = (int *)(ws + 87162880);
  int *planW = (int *)(ws + 87293952);
  int *fdesc = (int *)(ws + 87425024);
  const u32 *vzero = vstkH + 31 * 65536;

  // adaptive tail: optional xpk and Ppre ring
  const size_t fixed_end = 87426048;
  const size_t slotB = 1310720;   // 256*1280*4
  const size_t xpkB = 33554432;
  size_t avail = ws_size > fixed_end ? ws_size - fixed_end : 0;
  size_t tail = fixed_end;
  int use_xpk = 0;
  if (avail >= xpkB + 4 * slotB) { use_xpk = 1; tail += xpkB; avail -= xpkB; }
  u32 *xpk = (u32 *)(ws + fixed_end);  // valid only if use_xpk
  int R = (int)(avail / slotB);
  if (R > 32) R = 32;
  R &= ~1;
  int use_ppre = (R >= 2);
  int C = use_ppre ? R / 2 : 0;
  float *ppre = (float *)(ws + tail);

  pack_kernel<<<use_xpk ? 32768 : 2560, 256, 0, stream>>>(
      Wp, Wg, Wr, x, Wpg, Wr_t, xpk, vstkH, vstkC, use_xpk);
  plan_kernel<<<1, 256, 0, stream>>>(trans, planL, planR, planW, fdesc);
  if (use_xpk)
    front_kernel<1><<<dim3(2048, 2), 64, 0, stream>>>(x, xpk, Wpg, bp, bg, h_buf, c_buf);
  else
    front_kernel<0><<<dim3(2048, 2), 64, 0, stream>>>(x, xpk, Wpg, bp, bg, h_buf, c_buf);

  if (use_ppre) {
    int nch = (128 + C - 1) / C;
    auto pre = [&](int k) {
      int f0 = k * C;
      int Ck = min(C, 128 - f0);
      ppre_kernel<<<dim3(32, Ck * 16), 64, 0, stream>>>(
          br, Wr_t, h_buf, vzero, planL + f0 * 256, planR + f0 * 256,
          planW + f0 * 256, ppre + (size_t)((k & 1) * C) * 327680);
    };
    pre(0);
    if (nch > 1) pre(1);
    for (int k = 0; k < nch; ++k) {
      int f0 = k * C;
      int Ck = min(C, 128 - f0);
      for (int fl = 0; fl < Ck; ++fl) {
        int f = f0 + fl;
        step_kernel<1><<<dim3(32, 16), 64, 0, stream>>>(
            br, Wr_t, h_buf, c_buf, vstkH, vstkC, vzero, planL + f * 256,
            planR + f * 256, planW + f * 256,
            ppre + (size_t)((k & 1) * C + fl) * 327680);
      }
      if (k + 2 < nch) pre(k + 2);
    }
  } else {
    for (int f = 0; f < 128; ++f)
      step_kernel<0><<<dim3(32, 16), 64, 0, stream>>>(
          br, Wr_t, h_buf, c_buf, vstkH, vstkC, vzero, planL + f * 256,
          planR + f * 256, planW + f * 256, nullptr);
  }
  out_kernel<<<256, 256, 0, stream>>>(fdesc, h_buf, vstkH, out);
}